// Round 15
// baseline (3278.576 us; speedup 1.0000x reference)
//
#include <hip/hip_runtime.h>
#include <cmath>

// IDIM=256, CDIM=512, NH=2, N=128, M=64, T=64, BSZ=128
// x(t) = [emb(256) | reads0(64) | reads1(64) | h(512)], K=896, gate rows 2048.
// R15 = R8 proj/memops + FUSED gates+LSTM (kA): 3 nodes/step.
//  kA: grid 256 (128 ct x 2 half), 256 thr. Wave wid owns channel ch0+wid's
//  4 gate-rows over full K=896; lane = batch. x staged by global_load_lds in
//  double-buffered 14-k4 chunks (DMA overlaps compute, 1 barrier/chunk);
//  W read via wave-uniform (readfirstlane) addresses -> scalar loads from
//  XCD-local L2 (bid&127 pairing). No partials buffer at all.
//
// ---- ws float offsets ----
#define WS_EMBT  0                       // 2,097,152  [64 t][64 k4][128 b][4]
#define WS_STATE 2097152                 //   163,840  [2 par][160 ks][128 b][4]
#define WS_C     2260992                 //    65,536  c[b][512]
#define WS_MEM   2326528                 // 1,048,576  mem[b][128][64]
#define WS_RW    3375104                 //    32,768  [hi][b][128]
#define WS_WWS   3407872                 //    32,768
#define WS_PART  3440640                 //   557,056  part2 [8][128][544]
// total 3,997,696 floats (~16 MB)

// direct global->LDS 16B DMA; lds base wave-uniform (lane i -> base + i*16).
#define GLD16(g, l) __builtin_amdgcn_global_load_lds( \
    (const __attribute__((address_space(1))) void*)(g), \
    (__attribute__((address_space(3))) void*)(l), 16, 0, 0)

__device__ __forceinline__ float sigm(float x) { return 1.0f / (1.0f + expf(-x)); }
__device__ __forceinline__ float softplusf(float x) {
    return fmaxf(x, 0.0f) + log1pf(expf(-fabsf(x)));
}

// ---------------- one-time: transpose embs to k-major f4-packed ----------------
__global__ __launch_bounds__(256) void k_embT(const float* __restrict__ embs,
                                              float* __restrict__ ws)
{
    int f4 = blockIdx.x * 256 + threadIdx.x;        // 524288 float4s
    int k4 = f4 & 63, b = (f4 >> 6) & 127, t = f4 >> 13;
    float4 v = *(const float4*)&embs[(size_t)(t * 128 + b) * 256 + k4 * 4];
    *(float4*)&ws[WS_EMBT + ((size_t)(t * 64 + k4) * 128 + b) * 4] = v;
}

// ---------------- one-time: init state ----------------
__global__ __launch_bounds__(256) void k_init(float* __restrict__ ws,
                                              const float* __restrict__ mem_bias,
                                              const float* __restrict__ h0,
                                              const float* __restrict__ c0,
                                              const float* __restrict__ r0)
{
    int i = blockIdx.x * 256 + threadIdx.x;          // 1,261,568 total
    if (i < 81920) {                                  // stateT parity 0
        int ks = i >> 9, c4 = i & 3;
        int k = ks * 4 + c4;
        ws[WS_STATE + i] = (ks < 32) ? r0[k] : h0[k - 128];
        return;
    }
    int j = i - 81920;
    if (j < 65536) { ws[WS_C + j] = c0[j & 511]; return; }         // c[b][ch]
    j -= 65536;
    if (j < 1048576) { ws[WS_MEM + j] = mem_bias[j & 8191]; return; }
    j -= 1048576;
    ws[WS_RW + j] = 0.0f;                                          // rw + wws
}

// ---------------- kA: fused gates GEMM + LSTM pointwise ----------------
__device__ __forceinline__ void ka_issue_chunk(
    const float* __restrict__ embsT, const float* __restrict__ stateT,
    float4* __restrict__ xs4, int buf, int c, int tx, int wid, int half)
{
    // 896 f4 per chunk ([14 k4][64 b]); slot f = it*256+tx (lane-linear)
#pragma unroll
    for (int it = 0; it < 4; ++it) {
        int f = it * 256 + tx;
        if (it < 3 || tx < 128) {
            int k4g = c * 14 + (f >> 6);
            int b   = half * 64 + (f & 63);
            const float* gp = (k4g < 64)
                ? &embsT[(size_t)k4g * 512 + b * 4]
                : &stateT[(size_t)(k4g - 64) * 512 + b * 4];
            GLD16(gp, &xs4[buf * 896 + it * 256 + wid * 64]);
        }
    }
}

__global__ void __launch_bounds__(256) k_gates_lstm(
    const float* __restrict__ W_ih,   // (2048,384)
    const float* __restrict__ W_hh,   // (2048,512)
    const float* __restrict__ b_ih,
    const float* __restrict__ b_hh,
    float* __restrict__ ws,
    float* __restrict__ d_out,
    const int* __restrict__ lens,
    int t)
{
    __shared__ float xs[2 * 3584];        // [2 buf][14 k4][64 b] f4 = 28.7KB
    __shared__ float gx[16 * 64];         // [gate-row][b] 4KB
    float4* xs4 = (float4*)xs;

    const int tx = threadIdx.x;
    const int ct = blockIdx.x & 127, half = blockIdx.x >> 7;  // ct,ct+128 same XCD
    const int ch0 = ct * 4;
    const int p0 = t & 1, p1 = p0 ^ 1;
    const int lane = tx & 63, wid = tx >> 6;

    const float* embsT  = ws + WS_EMBT + (size_t)t * 32768;
    const float* stateT = ws + WS_STATE + (size_t)p0 * 81920;

    // wave-uniform W row bases (channel ch0+wid, gates 0..3) -> scalar loads
    const int chw = ch0 + __builtin_amdgcn_readfirstlane(wid);
    const float* pih0 = W_ih + (size_t)(0 * 512 + chw) * 384;
    const float* pih1 = W_ih + (size_t)(1 * 512 + chw) * 384;
    const float* pih2 = W_ih + (size_t)(2 * 512 + chw) * 384;
    const float* pih3 = W_ih + (size_t)(3 * 512 + chw) * 384;
    const float* phh0 = W_hh + (size_t)(0 * 512 + chw) * 512 - 384;
    const float* phh1 = W_hh + (size_t)(1 * 512 + chw) * 512 - 384;
    const float* phh2 = W_hh + (size_t)(2 * 512 + chw) * 512 - 384;
    const float* phh3 = W_hh + (size_t)(3 * 512 + chw) * 512 - 384;

    float acc0 = 0.f, acc1 = 0.f, acc2 = 0.f, acc3 = 0.f;

    ka_issue_chunk(embsT, stateT, xs4, 0, 0, tx, wid, half);
    int cur = 0;
    for (int c = 0; c < 16; ++c) {
        __syncthreads();                  // drains GLD16 of chunk c (vmcnt)
        if (c < 15)                       // DMA chunk c+1 under compute of c
            ka_issue_chunk(embsT, stateT, xs4, cur ^ 1, c + 1, tx, wid, half);
#pragma unroll
        for (int k4 = 0; k4 < 14; ++k4) {
            const int kg = c * 56 + k4 * 4;
            float4 xv = xs4[cur * 896 + k4 * 64 + lane];
            const bool ih = (kg < 384);
            float4 w0 = ih ? *(const float4*)&pih0[kg] : *(const float4*)&phh0[kg];
            float4 w1 = ih ? *(const float4*)&pih1[kg] : *(const float4*)&phh1[kg];
            float4 w2 = ih ? *(const float4*)&pih2[kg] : *(const float4*)&phh2[kg];
            float4 w3 = ih ? *(const float4*)&pih3[kg] : *(const float4*)&phh3[kg];
            acc0 += w0.x * xv.x + w0.y * xv.y + w0.z * xv.z + w0.w * xv.w;
            acc1 += w1.x * xv.x + w1.y * xv.y + w1.z * xv.z + w1.w * xv.w;
            acc2 += w2.x * xv.x + w2.y * xv.y + w2.z * xv.z + w2.w * xv.w;
            acc3 += w3.x * xv.x + w3.y * xv.y + w3.z * xv.z + w3.w * xv.w;
        }
        cur ^= 1;
    }

    // gate exchange: lds row = ch_l*4 + gate, ch_l = wid
    gx[(wid * 4 + 0) * 64 + lane] = acc0;
    gx[(wid * 4 + 1) * 64 + lane] = acc1;
    gx[(wid * 4 + 2) * 64 + lane] = acc2;
    gx[(wid * 4 + 3) * 64 + lane] = acc3;
    __syncthreads();

    // LSTM pointwise: thread -> (ch_l = tx&3, b_loc = tx>>2)
    {
        int ch_l = tx & 3, b_loc = tx >> 2;
        int b = half * 64 + b_loc;
        int ch = ch0 + ch_l;
        float gi = gx[(ch_l * 4 + 0) * 64 + b_loc] + b_ih[0 * 512 + ch] + b_hh[0 * 512 + ch];
        float gf = gx[(ch_l * 4 + 1) * 64 + b_loc] + b_ih[1 * 512 + ch] + b_hh[1 * 512 + ch];
        float gg = gx[(ch_l * 4 + 2) * 64 + b_loc] + b_ih[2 * 512 + ch] + b_hh[2 * 512 + ch];
        float go = gx[(ch_l * 4 + 3) * 64 + b_loc] + b_ih[3 * 512 + ch] + b_hh[3 * 512 + ch];
        float* cp = ws + WS_C + b * 512 + ch;
        float c_old = *cp;
        float c_new = sigm(gf) * c_old + sigm(gi) * tanhf(gg);
        float h_new = sigm(go) * tanhf(c_new);
        *cp = c_new;
        ws[WS_STATE + (size_t)p1 * 81920 + (32 + ct) * 512 + b * 4 + ch_l] = h_new;
        d_out[((size_t)t * 128 + b) * 640 + ch] = h_new;
        if (lens[b] - 1 == t) {
            d_out[5242880 + b * 512 + ch] = h_new;
            d_out[5308416 + b * 512 + ch] = c_new;
        }
    }
}

// ---------------- head projections GEMV-GEMM (R8 shape + parity) -------------
// grid 272 = 34 j-tiles(16) x 8 k-chunks(64); 256 thr. Reads h(t) at parity p1.
__global__ __launch_bounds__(256) void k_proj(
    const float* __restrict__ ws_c,
    const float* __restrict__ Wr,     // (2,70,512)
    const float* __restrict__ Ww,     // (2,198,512)
    float* __restrict__ part2,        // [kz][b][544]
    int t)
{
    __shared__ float w_s[16 * 64];        // 4KB
    __shared__ float x_s[16 * 128 * 4];   // 32KB
    float4* w_s4 = (float4*)w_s;
    float4* x_s4 = (float4*)x_s;

    const int tx = threadIdx.x;
    const int jt = blockIdx.x >> 3, kz = blockIdx.x & 7;
    const int j0 = jt * 16, k0 = kz * 64;
    const float* stateT = ws_c + WS_STATE + (size_t)((t + 1) & 1) * 81920;

    {
        int rl = tx >> 4, kq = tx & 15;
        int j = j0 + rl;
        float4 v = make_float4(0.f, 0.f, 0.f, 0.f);
        if (j < 536) {
            int hi = j >= 268, q = j - hi * 268;
            v = (q < 70) ? *(const float4*)&Wr[(hi * 70 + q) * 512 + k0 + kq * 4]
                         : *(const float4*)&Ww[(hi * 198 + (q - 70)) * 512 + k0 + kq * 4];
        }
        w_s4[tx] = v;
    }
#pragma unroll
    for (int it = 0; it < 8; ++it) {
        int f = it * 256 + tx;
        int k4 = f >> 7, b = f & 127;
        x_s4[f] = *(const float4*)&stateT[(size_t)(32 + kz * 16 + k4) * 512 + b * 4];
    }
    __syncthreads();

    const int lane = tx & 63, wid = tx >> 6;
    const int jw0 = wid * 4;
    float acc0[4] = {}, acc1[4] = {};
#pragma unroll 4
    for (int k4 = 0; k4 < 16; ++k4) {
        float4 xv0 = x_s4[k4 * 128 + lane];
        float4 xv1 = x_s4[k4 * 128 + 64 + lane];
#pragma unroll
        for (int r = 0; r < 4; ++r) {
            float4 wv = w_s4[(jw0 + r) * 16 + k4];
            acc0[r] += wv.x * xv0.x + wv.y * xv0.y + wv.z * xv0.z + wv.w * xv0.w;
            acc1[r] += wv.x * xv1.x + wv.y * xv1.y + wv.z * xv1.z + wv.w * xv1.w;
        }
    }
#pragma unroll
    for (int r = 0; r < 4; ++r) {
        int j = j0 + jw0 + r;
        if (j < 536) {
            part2[(size_t)kz * 69632 + lane * 544 + j]        = acc0[r];
            part2[(size_t)kz * 69632 + (lane + 64) * 544 + j] = acc1[r];
        }
    }
}

// ---------------- per-batch NTM memory ops (R8 shape + parity) ----------------
__global__ __launch_bounds__(256) void k_memops(
    const float* __restrict__ part2,  // [8][128][544]
    const float* __restrict__ br,     // (2,70)
    const float* __restrict__ bw,     // (2,198)
    float* __restrict__ ws,
    float* __restrict__ d_out,
    int t)
{
    const int b = blockIdx.x;
    const int tx = threadIdx.x;
    const int lx = tx & 127;
    const int grp = tx >> 7;          // 0 = read head, 1 = write head
    const int wid = tx >> 6;

    __shared__ float mem_s[128 * 66];
    __shared__ float proj_s[544];
    __shared__ float wg2_s[2 * 128];
    __shared__ float wf_s[2 * 128];
    __shared__ float red_s[16];
    __shared__ float ea_s[128];
    __shared__ float rvp_s[4 * 66];

    float* memg   = ws + WS_MEM;
    float* stateT = ws + WS_STATE + (size_t)((t + 1) & 1) * 81920;
    float* rwg    = ws + WS_RW;
    float* wwsg   = ws + WS_WWS;

    for (int j = tx; j < 536; j += 256) {
        int hi = j >= 268, q = j - hi * 268;
        float s = (q < 70) ? br[hi * 70 + q] : bw[hi * 198 + (q - 70)];
#pragma unroll
        for (int kzq = 0; kzq < 8; ++kzq)
            s += part2[(size_t)kzq * 69632 + b * 544 + j];
        proj_s[j] = s;
    }
#pragma unroll
    for (int e = 0; e < 8; ++e) {
        int f4 = e * 256 + tx;
        int n = f4 >> 4, m4 = (f4 & 15) * 4;
        float4 v = *(const float4*)&memg[b * 8192 + f4 * 4];
        *(float2*)&mem_s[n * 66 + m4]     = make_float2(v.x, v.y);
        *(float2*)&mem_s[n * 66 + m4 + 2] = make_float2(v.z, v.w);
    }
    __syncthreads();

    for (int hi = 0; hi < 2; ++hi) {
        const float* p = proj_s + hi * 268 + grp * 70;
        float* wprev_g = (grp == 0 ? rwg : wwsg) + (hi * 128 + b) * 128;

        float beta = softplusf(p[64]);
        float g = sigm(p[65]);
        float s0 = p[66], s1 = p[67], s2 = p[68];
        float sm = fmaxf(s0, fmaxf(s1, s2));
        float e0 = expf(s0 - sm), e1 = expf(s1 - sm), e2 = expf(s2 - sm);
        float sden = e0 + e1 + e2;
        s0 = e0 / sden; s1 = e1 / sden; s2 = e2 / sden;
        float gamma = 1.0f + softplusf(p[69]);

        const float* mrow = mem_s + lx * 66;
        float dot = 0.f, nm = 0.f, nk = 0.f;
#pragma unroll
        for (int m = 0; m < 64; m += 2) {
            float2 kv2 = *(const float2*)&p[m];
            float2 mv2 = *(const float2*)&mrow[m];
            float kx = kv2.x + 1e-16f, ky = kv2.y + 1e-16f;
            float mx = mv2.x + 1e-16f, my = mv2.y + 1e-16f;
            dot += mx * kx + my * ky;
            nm  += mx * mx + my * my;
            nk  += kx * kx + ky * ky;
        }
        float sim = dot / fmaxf(sqrtf(nm) * sqrtf(nk), 1e-8f);
        float z = beta * sim;

        float r = z;
#pragma unroll
        for (int d = 32; d > 0; d >>= 1) r = fmaxf(r, __shfl_xor(r, d));
        if ((tx & 63) == 0) red_s[wid] = r;
        __syncthreads();
        float zmax = fmaxf(red_s[grp * 2], red_s[grp * 2 + 1]);
        float ez = expf(z - zmax);
        r = ez;
#pragma unroll
        for (int d = 32; d > 0; d >>= 1) r += __shfl_xor(r, d);
        if ((tx & 63) == 0) red_s[8 + wid] = r;
        __syncthreads();
        float zsum = red_s[8 + grp * 2] + red_s[8 + grp * 2 + 1];
        float wc = ez / zsum;
        float wgv = g * wc + (1.f - g) * wprev_g[lx];
        wg2_s[grp * 128 + lx] = wgv;
        __syncthreads();
        float wwv = s0 * wg2_s[grp * 128 + ((lx + 127) & 127)] + s1 * wgv
                  + s2 * wg2_s[grp * 128 + ((lx + 1) & 127)];
        float wp = powf(wwv, gamma);
        r = wp;
#pragma unroll
        for (int d = 32; d > 0; d >>= 1) r += __shfl_xor(r, d);
        if ((tx & 63) == 0) red_s[wid] = r;
        __syncthreads();
        float psum = red_s[grp * 2] + red_s[grp * 2 + 1];
        float wfin = wp / (psum + 1e-16f);
        wf_s[grp * 128 + lx] = wfin;
        wprev_g[lx] = wfin;
        __syncthreads();

        {
            int m = tx & 63, p4 = tx >> 6;
            float rv = 0.f;
            const int nb = p4 * 32;
#pragma unroll
            for (int n8 = 0; n8 < 32; ++n8) {
                int n = nb + n8;
                rv += wf_s[n] * mem_s[n * 66 + m];
            }
            rvp_s[p4 * 66 + m] = rv;
        }
        if (tx < 64)        ea_s[tx] = sigm(proj_s[hi * 268 + 140 + tx]);
        else if (tx < 128)  ea_s[tx] = proj_s[hi * 268 + 204 + (tx - 64)];
        __syncthreads();

        if (tx < 64) {
            float rvf = rvp_s[tx] + rvp_s[66 + tx] + rvp_s[132 + tx] + rvp_s[198 + tx];
            stateT[((hi * 64 + tx) >> 2) * 512 + b * 4 + (tx & 3)] = rvf;
            d_out[((size_t)t * 128 + b) * 640 + 512 + hi * 64 + tx] = rvf;
        }
#pragma unroll
        for (int e = 0; e < 16; ++e) {
            int f = e * 256 + tx;
            int n = f >> 5, m2 = (f & 31) * 2;
            float w2 = wf_s[128 + n];
            float2 mv = *(const float2*)&mem_s[n * 66 + m2];
            mv.x = mv.x * (1.f - w2 * ea_s[m2])     + w2 * ea_s[64 + m2];
            mv.y = mv.y * (1.f - w2 * ea_s[m2 + 1]) + w2 * ea_s[65 + m2];
            *(float2*)&mem_s[n * 66 + m2] = mv;
            if (hi == 1) *(float2*)&memg[b * 8192 + f * 2] = mv;
        }
        __syncthreads();
    }
}

// ---------------- host ----------------
extern "C" void kernel_launch(void* const* d_in, const int* in_sizes, int n_in,
                              void* d_out, int out_size, void* d_ws, size_t ws_size,
                              hipStream_t stream)
{
    (void)in_sizes; (void)n_in; (void)out_size; (void)ws_size;
    const float* embs     = (const float*)d_in[0];
    const int*   lens     = (const int*)  d_in[1];
    const float* mem_bias = (const float*)d_in[2];
    const float* W_ih     = (const float*)d_in[3];
    const float* W_hh     = (const float*)d_in[4];
    const float* b_ih     = (const float*)d_in[5];
    const float* b_hh     = (const float*)d_in[6];
    const float* Wr       = (const float*)d_in[7];
    const float* br       = (const float*)d_in[8];
    const float* Ww       = (const float*)d_in[9];
    const float* bw       = (const float*)d_in[10];
    const float* h0       = (const float*)d_in[11];
    const float* c0       = (const float*)d_in[12];
    const float* r0       = (const float*)d_in[13];
    float* out = (float*)d_out;
    float* ws  = (float*)d_ws;
    float* part2 = ws + WS_PART;

    k_embT<<<2048, 256, 0, stream>>>(embs, ws);
    k_init<<<4928, 256, 0, stream>>>(ws, mem_bias, h0, c0, r0);
    for (int t = 0; t < 64; ++t) {
        k_gates_lstm<<<256, 256, 0, stream>>>(W_ih, W_hh, b_ih, b_hh,
                                              ws, out, lens, t);
        k_proj<<<272, 256, 0, stream>>>(ws, Wr, Ww, part2, t);
        k_memops<<<128, 256, 0, stream>>>(part2, br, bw, ws, out, t);
    }
}